// Round 5
// baseline (400.056 us; speedup 1.0000x reference)
//
#include <hip/hip_runtime.h>
#include <cfloat>

// Problem constants
#define T_TOTAL 32768   // 32*32*32 spatial positions
#define DIM 64          // embedding dim
#define KCODES 1024     // num embeddings

// native 2x-float vector for nontemporal builtins (HIP float2 is a class type)
typedef float f32x2 __attribute__((ext_vector_type(2)));

// d_out flat layout (fp32 elements), reference return order:
//   quantized_out [32,64,32,32] = 2097152
//   loss (1), perplexity (1)
//   encodings [32768,1024] = 33554432
//   distances [32768,1024] = 33554432
static constexpr long long OFF_Q    = 0;
static constexpr long long OFF_LOSS = 2097152;
static constexpr long long OFF_PERP = 2097153;
static constexpr long long OFF_ENC  = 2097154;            // 8B aligned only -> float2 max
static constexpr long long OFF_DIST = 2097154LL + 33554432LL; // 8B aligned only -> float2 max

// ws layout: [0,4096) int counts[1024]; [4096,8192) float ww[1024];
//            [8192,8196) float lossSum; [12288, 12288+256K) float WT[64][1024]

// ---------------------------------------------------------------------------
// Prep: ||w_k||^2 (blocks 0..255) + W transpose WT[n][k] (blocks 256..319).
__global__ __launch_bounds__(256) void vq_prep_kernel(const float* __restrict__ W,
                                                      float* __restrict__ ww,
                                                      float* __restrict__ WT) {
    const int tid = threadIdx.x;
    if (blockIdx.x < 256) {
        const int lane = tid & 63;
        const int code = blockIdx.x * 4 + (tid >> 6);
        float v = W[code * DIM + lane];
        float s = v * v;
        #pragma unroll
        for (int off = 32; off > 0; off >>= 1)
            s += __shfl_down(s, off, 64);
        if (lane == 0) ww[code] = s;
    } else {
        const int n = blockIdx.x - 256;   // 0..63
        #pragma unroll
        for (int i = 0; i < 4; ++i) {
            int k = i * 256 + tid;
            WT[n * KCODES + k] = W[k * DIM + n];
        }
    }
}

// ---------------------------------------------------------------------------
// Main fused kernel. 1024 blocks x 256 threads; block owns 32 rows.
// Wave rg handles rows rg*8..rg*8+7. b-fragments read DIRECTLY from global WT
// (L1/L2-resident, all waves read identical addresses) -> ZERO barriers in the
// K-loop; dist stores stream with no vmcnt(0) drains until the epilogue.
__global__ __launch_bounds__(256, 4) void vq_main_kernel(const float* __restrict__ lat,
                                                         const float* __restrict__ W,
                                                         const float* __restrict__ ww,
                                                         const float* __restrict__ WT,
                                                         float* __restrict__ out,
                                                         int* __restrict__ counts,
                                                         float* __restrict__ lossSum) {
    __shared__ float xT[64 * 32];      // [n][tl] 8 KB — persistent
    __shared__ float xx[32];           // ||x_row||^2
    __shared__ float qS[32 * 65];      // gathered codes, +1 pad
    __shared__ int   selS[32];

    const int tid = threadIdx.x;
    const int ct  = tid & 63;          // lane within wave
    const int rg  = tid >> 6;          // wave id == row group (rows rg*8..rg*8+7)
    const int t0  = blockIdx.x * 32;
    // flat row t -> latent addr b*65536 + n*1024 + (j*32+d); 32-row block stays in one b
    const long long base = (long long)(t0 >> 10) * 65536 + (long long)(t0 & 1023);

    // ---- stage x tile (8 KB) + fold ||x||^2 partials into the same pass
    if (tid < 32) xx[tid] = 0.f;
    __syncthreads();
    {
        float sp = 0.f;
        #pragma unroll
        for (int i = 0; i < 8; ++i) {
            int e  = i * 256 + tid;    // == n*32 + tl ; tl = tid&31 fixed per thread
            int n  = e >> 5;
            int tl = e & 31;
            float v = lat[base + (long long)n * 1024 + tl];
            xT[e] = v;
            sp = fmaf(v, v, sp);
        }
        atomicAdd(&xx[tid & 31], sp);  // ds_add_f32, 8-way per slot, once
    }
    __syncthreads();

    float minV[8];
    int   minI[8];
    #pragma unroll
    for (int r = 0; r < 8; ++r) { minV[r] = FLT_MAX; minI[r] = 0; }

    float* __restrict__ distOut = out + OFF_DIST;

    // ================= barrier-free K-loop: 4 chunks of 256 codes ==========
    for (int c = 0; c < 4; ++c) {
        float acc[8][4];
        #pragma unroll
        for (int r = 0; r < 8; ++r)
            #pragma unroll
            for (int k = 0; k < 4; ++k) acc[r][k] = 0.f;

        const float* __restrict__ wp = WT + c * 256 + ct * 2;
        #pragma unroll 4
        for (int n = 0; n < 64; ++n) {
            float4 a0 = *(const float4*)&xT[n * 32 + rg * 8];      // full-wave broadcast
            float4 a1 = *(const float4*)&xT[n * 32 + rg * 8 + 4];
            float2 b0 = *(const float2*)&wp[n * KCODES];           // L1-hit, 512B dense
            float2 b1 = *(const float2*)&wp[n * KCODES + 128];
            float ar[8] = {a0.x, a0.y, a0.z, a0.w, a1.x, a1.y, a1.z, a1.w};
            float br[4] = {b0.x, b0.y, b1.x, b1.y};
            #pragma unroll
            for (int r = 0; r < 8; ++r)
                #pragma unroll
                for (int k = 0; k < 4; ++k)
                    acc[r][k] = fmaf(ar[r], br[k], acc[r][k]);
        }

        // ---- distances (nontemporal) + running argmin (strict <, ascending k)
        const int kb = c * 256 + ct * 2;   // cols kb, kb+1, kb+128, kb+129
        float2 w0 = *(const float2*)&ww[kb];
        float2 w1 = *(const float2*)&ww[kb + 128];
        #pragma unroll
        for (int r = 0; r < 8; ++r) {
            const int row = rg * 8 + r;
            const float xxr = xx[row];
            float d0 = (xxr + w0.x) - 2.f * acc[r][0];
            float d1 = (xxr + w0.y) - 2.f * acc[r][1];
            float d2 = (xxr + w1.x) - 2.f * acc[r][2];
            float d3 = (xxr + w1.y) - 2.f * acc[r][3];
            if (d0 < minV[r]) { minV[r] = d0; minI[r] = kb; }
            if (d1 < minV[r]) { minV[r] = d1; minI[r] = kb + 1; }
            if (d2 < minV[r]) { minV[r] = d2; minI[r] = kb + 128; }
            if (d3 < minV[r]) { minV[r] = d3; minI[r] = kb + 129; }
            const long long ro = (long long)(t0 + row) * KCODES + kb;
            f32x2 v01; v01.x = d0; v01.y = d1;
            f32x2 v23; v23.x = d2; v23.y = d3;
            __builtin_nontemporal_store(v01, (f32x2*)&distOut[ro]);
            __builtin_nontemporal_store(v23, (f32x2*)&distOut[ro + 128]);
        }
    }

    // ---- per-row argmin across the wave via shuffles; broadcast to all lanes
    int selR[8];
    #pragma unroll
    for (int r = 0; r < 8; ++r) {
        float v  = minV[r];
        int   i0 = minI[r];
        #pragma unroll
        for (int off = 32; off > 0; off >>= 1) {
            float v2 = __shfl_down(v, off, 64);
            int   i2 = __shfl_down(i0, off, 64);
            if (v2 < v || (v2 == v && i2 < i0)) { v = v2; i0 = i2; }
        }
        int sel = __shfl(i0, 0, 64);
        selR[r] = sel;
        if (ct == 0) {
            selS[rg * 8 + r] = sel;
            atomicAdd(&counts[sel], 1);
        }
    }
    __syncthreads();

    // ---- gather selected codebook rows into LDS (stride 65 kills conflicts)
    #pragma unroll
    for (int i = 0; i < 8; ++i) {
        int e   = i * 256 + tid;
        int row = e >> 6;
        int n   = e & 63;
        qS[row * 65 + n] = W[selS[row] * DIM + n];
    }
    __syncthreads();

    // ---- quantized_out (dense float4) + loss partial
    float ls = 0.f;
    #pragma unroll
    for (int i = 0; i < 2; ++i) {
        int e2  = i * 256 + tid;       // [0,512) float4 slots
        int n   = e2 >> 3;             // 0..63
        int tl0 = (e2 & 7) * 4;
        float q0 = qS[(tl0 + 0) * 65 + n];
        float q1 = qS[(tl0 + 1) * 65 + n];
        float q2 = qS[(tl0 + 2) * 65 + n];
        float q3 = qS[(tl0 + 3) * 65 + n];
        float4 xv = *(const float4*)&xT[n * 32 + tl0];
        *(float4*)&out[OFF_Q + base + (long long)n * 1024 + tl0] = make_float4(q0, q1, q2, q3);
        float e0 = q0 - xv.x; ls = fmaf(e0, e0, ls);
        float e1 = q1 - xv.y; ls = fmaf(e1, e1, ls);
        float e2d = q2 - xv.z; ls = fmaf(e2d, e2d, ls);
        float e3 = q3 - xv.w; ls = fmaf(e3, e3, ls);
    }
    #pragma unroll
    for (int off = 32; off > 0; off >>= 1)
        ls += __shfl_down(ls, off, 64);
    if (ct == 0) atomicAdd(lossSum, ls);

    // ---- one-hot encodings LAST (nontemporal, no trailing barrier; wave-local)
    float* __restrict__ enc = out + OFF_ENC;
    #pragma unroll
    for (int r = 0; r < 8; ++r) {
        const int sel = selR[r];
        const long long rowbase = (long long)(t0 + rg * 8 + r) * KCODES;
        #pragma unroll
        for (int i = 0; i < 8; ++i) {
            int k2 = (i * 64 + ct) * 2;
            f32x2 v;
            v.x = (k2     == sel) ? 1.f : 0.f;
            v.y = (k2 + 1 == sel) ? 1.f : 0.f;
            __builtin_nontemporal_store(v, (f32x2*)&enc[rowbase + k2]);
        }
    }
}

// ---------------------------------------------------------------------------
// Finalize: perplexity from histogram, loss from accumulated SSE.
__global__ __launch_bounds__(1024) void vq_finalize_kernel(const int* __restrict__ counts,
                                                           const float* __restrict__ lossSum,
                                                           float* __restrict__ out) {
    __shared__ float red[16];
    const int tid = threadIdx.x;
    float p = (float)counts[tid] * (1.0f / 32768.0f);   // exact (pow2 divisor)
    float term = p * logf(p + 1e-10f);
    #pragma unroll
    for (int off = 32; off > 0; off >>= 1)
        term += __shfl_down(term, off, 64);
    if ((tid & 63) == 0) red[tid >> 6] = term;
    __syncthreads();
    if (tid == 0) {
        float s = 0.f;
        #pragma unroll
        for (int i = 0; i < 16; ++i) s += red[i];
        out[OFF_PERP] = expf(-s);
        out[OFF_LOSS] = 0.25f * lossSum[0] * (1.0f / 2097152.0f);  // COMMIT_COST * mean SSE
    }
}

// ---------------------------------------------------------------------------
extern "C" void kernel_launch(void* const* d_in, const int* in_sizes, int n_in,
                              void* d_out, int out_size, void* d_ws, size_t ws_size,
                              hipStream_t stream) {
    (void)in_sizes; (void)n_in; (void)out_size; (void)ws_size;
    const float* lat = (const float*)d_in[0];   // [32,64,32,32]
    const float* W   = (const float*)d_in[1];   // [1024,64]
    float* out = (float*)d_out;

    int*   counts  = (int*)d_ws;
    float* ww      = (float*)((char*)d_ws + 4096);
    float* lossSum = (float*)((char*)d_ws + 8192);
    float* WT      = (float*)((char*)d_ws + 12288);   // 64x1024 fp32 = 256 KB

    // zero counts + lossSum (ww/WT fully overwritten by vq_prep_kernel)
    (void)hipMemsetAsync(d_ws, 0, 8192 + 16, stream);

    vq_prep_kernel<<<320, 256, 0, stream>>>(W, ww, WT);
    vq_main_kernel<<<1024, 256, 0, stream>>>(lat, W, ww, WT, out, counts, lossSum);
    vq_finalize_kernel<<<1, 1024, 0, stream>>>(counts, lossSum, out);
}